// Round 1
// baseline (224.830 us; speedup 1.0000x reference)
//
#include <hip/hip_runtime.h>

#define HH 448
#define WW 512
#define NPIX (HH * WW)

struct Res { int idx; float ent; };

__device__ __forceinline__ float lrelu(float v) { return v > 0.0f ? v : 0.01f * v; }

// argmax (first occurrence of max, like jnp.argmax) + entropy of softmax over 16 logits
__device__ __forceinline__ Res argmax_ent16(const float* __restrict__ v) {
    float m = v[0]; int idx = 0;
#pragma unroll
    for (int i = 1; i < 16; i++) { if (v[i] > m) { m = v[i]; idx = i; } }
    float s = 0.0f, dot = 0.0f;
#pragma unroll
    for (int i = 0; i < 16; i++) {
        float t = __expf(v[i] - m);
        s += t;
        dot = fmaf(t, v[i], dot);
    }
    Res r; r.idx = idx; r.ent = m + __logf(s) - dot / s;
    return r;
}

// y[o] = b[o] + sum_i x[i] * w[i*OUT + o]   (global weights, layout [in][out])
template <int OUT>
__device__ __forceinline__ void layer_g(const float* __restrict__ wmat,
                                        const float* __restrict__ bias,
                                        const float* __restrict__ x,
                                        float* __restrict__ y) {
    float acc[OUT];
#pragma unroll
    for (int o = 0; o < OUT; o++) acc[o] = bias[o];
#pragma unroll
    for (int i = 0; i < 32; i++) {
        float xi = x[i];
        const float4* row = (const float4*)(wmat + i * OUT);
#pragma unroll
        for (int q = 0; q < OUT / 4; q++) {
            float4 wv = row[q];
            acc[4 * q + 0] = fmaf(xi, wv.x, acc[4 * q + 0]);
            acc[4 * q + 1] = fmaf(xi, wv.y, acc[4 * q + 1]);
            acc[4 * q + 2] = fmaf(xi, wv.z, acc[4 * q + 2]);
            acc[4 * q + 3] = fmaf(xi, wv.w, acc[4 * q + 3]);
        }
    }
#pragma unroll
    for (int o = 0; o < OUT; o++) y[o] = acc[o];
}

// y[o] = b[o] + sum_i x[i] * w[o*32 + i]   (LDS weights, layout [out][in]; broadcast reads)
template <int OUT>
__device__ __forceinline__ void layer_lds(const float* __restrict__ sw,
                                          const float* __restrict__ sb,
                                          const float* __restrict__ x,
                                          float* __restrict__ y) {
#pragma unroll
    for (int o = 0; o < OUT; o++) {
        const float4* row = (const float4*)(sw + o * 32);
        float a = sb[o];
#pragma unroll
        for (int q = 0; q < 8; q++) {
            float4 wv = row[q];
            a = fmaf(wv.x, x[4 * q + 0], a);
            a = fmaf(wv.y, x[4 * q + 1], a);
            a = fmaf(wv.z, x[4 * q + 2], a);
            a = fmaf(wv.w, x[4 * q + 3], a);
        }
        y[o] = a;
    }
}

// full 3-layer expert MLP (32->32->32->16) + argmax/entropy. Emitted once (noinline).
__device__ __noinline__ Res condmul3(const float* __restrict__ xbase, int p,
                                     const float* __restrict__ w0, const float* __restrict__ b0,
                                     const float* __restrict__ w1, const float* __restrict__ b1,
                                     const float* __restrict__ w2, const float* __restrict__ b2,
                                     long e) {
    float x[32], y[32];
#pragma unroll
    for (int c = 0; c < 32; c++) x[c] = xbase[(size_t)c * NPIX + p];
    layer_g<32>(w0 + (size_t)e * 1024, b0 + (size_t)e * 32, x, y);
#pragma unroll
    for (int o = 0; o < 32; o++) y[o] = lrelu(y[o]);
    layer_g<32>(w1 + (size_t)e * 1024, b1 + (size_t)e * 32, y, x);
#pragma unroll
    for (int o = 0; o < 32; o++) x[o] = lrelu(x[o]);
    float z[16];
    layer_g<16>(w2 + (size_t)e * 512, b2 + (size_t)e * 16, x, z);
    return argmax_ent16(z);
}

__global__ __launch_bounds__(512) void cls3_kernel(
    const float* __restrict__ x_in,
    const float* __restrict__ w1_0, const float* __restrict__ b1_0,
    const float* __restrict__ w1_1, const float* __restrict__ b1_1,
    const float* __restrict__ w1_2, const float* __restrict__ b1_2,
    const float* __restrict__ w2_0, const float* __restrict__ b2_0,
    const float* __restrict__ w2_1, const float* __restrict__ b2_1,
    const float* __restrict__ w2_2, const float* __restrict__ b2_2,
    const float* __restrict__ w3_0, const float* __restrict__ b3_0,
    const float* __restrict__ w3_1, const float* __restrict__ b3_1,
    const float* __restrict__ w3_2, const float* __restrict__ b3_2,
    float* __restrict__ out) {
    __shared__ float s1[2640];   // w1_0[1024] w1_1[1024] w1_2[512] b1_0[32] b1_1[32] b1_2[16]
    __shared__ int sCls[512];
    __shared__ int sRaw[512];
    __shared__ int sPerm[512];
    __shared__ int sCnt[192];
    __shared__ int sScan[192];
    __shared__ int sOffs[192];

    const int h = blockIdx.x;
    const int t = threadIdx.x;

    // ---- stage-1 weight staging into LDS (layout [out][in], as in global) ----
    {
        const float* g0 = w1_0 + (size_t)h * 1024;
        const float* g1 = w1_1 + (size_t)h * 1024;
        for (int idx = t; idx < 1024; idx += 512) {
            s1[idx] = g0[idx];
            s1[1024 + idx] = g1[idx];
        }
        s1[2048 + t] = (t < 512) ? w1_2[(size_t)h * 512 + t] : 0.0f;
        if (t < 32) {
            s1[2560 + t] = b1_0[(size_t)h * 32 + t];
            s1[2592 + t] = b1_1[(size_t)h * 32 + t];
        }
        if (t < 16) s1[2624 + t] = b1_2[(size_t)h * 16 + t];
    }
    __syncthreads();

    // ---- stage 1: per-pixel 3-layer MLP from LDS weights ----
    {
        float x[32], y[32], z16[16];
#pragma unroll
        for (int c = 0; c < 32; c++) x[c] = x_in[(size_t)c * NPIX + (size_t)h * WW + t];
        layer_lds<32>(s1, s1 + 2560, x, y);
#pragma unroll
        for (int o = 0; o < 32; o++) y[o] = lrelu(y[o]);
        layer_lds<32>(s1 + 1024, s1 + 2592, y, x);
#pragma unroll
        for (int o = 0; o < 32; o++) x[o] = lrelu(x[o]);
        layer_lds<16>(s1 + 2048, s1 + 2624, x, z16);
        Res r = argmax_ent16(z16);
        out[NPIX + (size_t)h * WW + t] = r.ent;  // e1
        sCls[t] = r.idx;                         // inds1 in [0,16)
    }
    __syncthreads();

    // ---- counting sort by inds1 (16 bins) ----
    if (t < 192) sCnt[t] = 0;
    __syncthreads();
    int rank = atomicAdd(&sCnt[sCls[t]], 1);
    __syncthreads();
    if (t < 192) {
        int v = sCnt[t];
        int incl = v;
#pragma unroll
        for (int d = 1; d < 64; d <<= 1) {
            int n = __shfl_up(incl, d, 64);
            if ((t & 63) >= d) incl += n;
        }
        sScan[t] = incl;
    }
    __syncthreads();
    if (t < 192) {
        int add = 0;
        if (t >= 64) add += sScan[63];
        if (t >= 128) add += sScan[127];
        sOffs[t] = sScan[t] + add - sCnt[t];  // exclusive prefix
    }
    __syncthreads();
    sPerm[sOffs[sCls[t]] + rank] = t;
    __syncthreads();

    // ---- stage 2: CondMul cascade, pixels processed in class-sorted order ----
    {
        int p = sPerm[t];
        int c1 = sCls[p];
        long e = (long)h * 16 + c1;
        Res r = condmul3(x_in + (size_t)32 * NPIX + (size_t)h * WW, p,
                         w2_0, b2_0, w2_1, b2_1, w2_2, b2_2, e);
        out[2 * NPIX + (size_t)h * WW + p] = r.ent;  // e2
        int raw = c1 * 12 + r.idx - 2;               // inds12 (unclipped)
        sRaw[p] = raw;
        int cl = raw < 0 ? 0 : (raw > 191 ? 191 : raw);
        sCls[p] = cl;  // own slot only (sPerm is a permutation) -> no race
    }
    __syncthreads();

    // ---- counting sort by clipped inds12 (192 bins) ----
    if (t < 192) sCnt[t] = 0;
    __syncthreads();
    rank = atomicAdd(&sCnt[sCls[t]], 1);
    __syncthreads();
    if (t < 192) {
        int v = sCnt[t];
        int incl = v;
#pragma unroll
        for (int d = 1; d < 64; d <<= 1) {
            int n = __shfl_up(incl, d, 64);
            if ((t & 63) >= d) incl += n;
        }
        sScan[t] = incl;
    }
    __syncthreads();
    if (t < 192) {
        int add = 0;
        if (t >= 64) add += sScan[63];
        if (t >= 128) add += sScan[127];
        sOffs[t] = sScan[t] + add - sCnt[t];
    }
    __syncthreads();
    sPerm[sOffs[sCls[t]] + rank] = t;
    __syncthreads();

    // ---- stage 3 ----
    {
        int p = sPerm[t];
        int cl = sCls[p];
        int raw = sRaw[p];
        long e = (long)h * 192 + cl;
        Res r = condmul3(x_in + (size_t)64 * NPIX + (size_t)h * WW, p,
                         w3_0, b3_0, w3_1, b3_1, w3_2, b3_2, e);
        out[3 * NPIX + (size_t)h * WW + p] = r.ent;  // e3
        int i123 = raw * 8 + r.idx - 4;
        i123 = i123 < 0 ? 0 : (i123 > 1535 ? 1535 : i123);
        out[(size_t)h * WW + p] = (float)i123;       // inds123 as float
    }
}

extern "C" void kernel_launch(void* const* d_in, const int* in_sizes, int n_in,
                              void* d_out, int out_size, void* d_ws, size_t ws_size,
                              hipStream_t stream) {
    const float* P[19];
    for (int i = 0; i < 19 && i < n_in; i++) P[i] = (const float*)d_in[i];

    const float *x_in, *W1[3], *B1[3], *W2[3], *B2[3], *W3[3], *B3[3];
    x_in = P[0];
    // setup_inputs() dict order interleaves w/b: w1_0,b1_0,w1_1,b1_1,...  (in_sizes[2]==448*32)
    // reference-signature order would give in_sizes[2]==448*32*32.
    bool dict_order = (in_sizes[2] == 448 * 32);
    if (dict_order) {
        W1[0] = P[1];  B1[0] = P[2];  W1[1] = P[3];  B1[1] = P[4];  W1[2] = P[5];  B1[2] = P[6];
        W2[0] = P[7];  B2[0] = P[8];  W2[1] = P[9];  B2[1] = P[10]; W2[2] = P[11]; B2[2] = P[12];
        W3[0] = P[13]; B3[0] = P[14]; W3[1] = P[15]; B3[1] = P[16]; W3[2] = P[17]; B3[2] = P[18];
    } else {
        W1[0] = P[1];  W1[1] = P[2];  W1[2] = P[3];  B1[0] = P[4];  B1[1] = P[5];  B1[2] = P[6];
        W2[0] = P[7];  W2[1] = P[8];  W2[2] = P[9];  B2[0] = P[10]; B2[1] = P[11]; B2[2] = P[12];
        W3[0] = P[13]; W3[1] = P[14]; W3[2] = P[15]; B3[0] = P[16]; B3[1] = P[17]; B3[2] = P[18];
    }

    float* out = (float*)d_out;
    dim3 grid(HH), block(WW);
    hipLaunchKernelGGL(cls3_kernel, grid, block, 0, stream,
                       x_in,
                       W1[0], B1[0], W1[1], B1[1], W1[2], B1[2],
                       W2[0], B2[0], W2[1], B2[1], W2[2], B2[2],
                       W3[0], B3[0], W3[1], B3[1], W3[2], B3[2],
                       out);
}